// Round 1
// baseline (607.302 us; speedup 1.0000x reference)
//
#include <hip/hip_runtime.h>
#include <hip/hip_bf16.h>
#include <stdint.h>

// Problem dims (fixed by reference): x (4,2048,4096) f32, W (4096,4096) f32,
// bias (4096) f32, sparsity_scale (4096) f32. Tokens T = 8192.
#define T_TOK 8192
#define K_DIM 4096
#define N_DIM 4096

typedef short bf16x8 __attribute__((ext_vector_type(8)));
typedef float f32x4  __attribute__((ext_vector_type(4)));

// RTNE f32 -> bf16 (bit manipulation; matches numpy/jax casts for finite vals)
__device__ __forceinline__ unsigned short f2bf(float f) {
    uint32_t u = __float_as_uint(f);
    u += 0x7FFFu + ((u >> 16) & 1u);
    return (unsigned short)(u >> 16);
}

// async global->LDS, 16B per lane. LDS dest must be wave-uniform base + lane*16.
__device__ __forceinline__ void gload_lds16(const void* g, void* l) {
    __builtin_amdgcn_global_load_lds(
        (const __attribute__((address_space(1))) void*)g,
        (__attribute__((address_space(3))) void*)l, 16, 0, 0);
}

// ---------------- kernel 0: W f32 -> bf16 ----------------
__global__ __launch_bounds__(256) void wconv_kernel(const float* __restrict__ w,
                                                    unsigned short* __restrict__ wb) {
    int i = (blockIdx.x * 256 + threadIdx.x) * 4;   // 4 floats per thread
    float4 v = *(const float4*)(w + i);
    ushort4 o;
    o.x = f2bf(v.x); o.y = f2bf(v.y); o.z = f2bf(v.z); o.w = f2bf(v.w);
    *(ushort4*)(wb + i) = o;
}

// ------- kernel 1: 2:4 sparsify + per-token absmax quant -> qi (bf16 ints), s -------
// one block (256 thr) per token row; each thread owns 4 groups of 4 consecutive cols
__global__ __launch_bounds__(256) void sparsequant_kernel(
        const float* __restrict__ x, const float* __restrict__ ss,
        unsigned short* __restrict__ qi, float* __restrict__ scales) {
    const int row = blockIdx.x;
    const int t = threadIdx.x;
    const float* xr = x + (size_t)row * K_DIM;

    float xs[16];
    float amax = 0.f;
#pragma unroll
    for (int j = 0; j < 4; ++j) {
        int g = t + 256 * j;                     // group index 0..1023
        float4 v  = ((const float4*)xr)[g];
        float4 sv = ((const float4*)ss)[g];
        float e[4] = { v.x, v.y, v.z, v.w };
        float m[4] = { fabsf(v.x) * sv.x, fabsf(v.y) * sv.y,
                       fabsf(v.z) * sv.z, fabsf(v.w) * sv.w };
#pragma unroll
        for (int a = 0; a < 4; ++a) {
            int cnt = 0;
#pragma unroll
            for (int b = 0; b < 4; ++b) {
                if (b == a) continue;
                // strict-order key (metric, index): matches stable top_k of smallest
                bool less = (m[b] < m[a]) || (m[b] == m[a] && b < a);
                cnt += less ? 1 : 0;
            }
            float kept = (cnt >= 2) ? e[a] : 0.f;   // zero the 2 smallest
            xs[j * 4 + a] = kept;
            amax = fmaxf(amax, fabsf(kept));
        }
    }
    // block max over 256 threads
#pragma unroll
    for (int off = 32; off >= 1; off >>= 1)
        amax = fmaxf(amax, __shfl_xor(amax, off, 64));
    __shared__ float wm[4];
    int wave = t >> 6, lane = t & 63;
    if (lane == 0) wm[wave] = amax;
    __syncthreads();
    amax = fmaxf(fmaxf(wm[0], wm[1]), fmaxf(wm[2], wm[3]));

    float s = fmaxf(amax, 1e-5f) / 127.0f;   // same f32 ops as reference
    if (t == 0) scales[row] = s;

    unsigned short* qr = qi + (size_t)row * K_DIM;
#pragma unroll
    for (int j = 0; j < 4; ++j) {
        int g = t + 256 * j;
        ushort4 o;
        o.x = f2bf(rintf(xs[j * 4 + 0] / s));    // RTNE div+round, ints exact in bf16
        o.y = f2bf(rintf(xs[j * 4 + 1] / s));
        o.z = f2bf(rintf(xs[j * 4 + 2] / s));
        o.w = f2bf(rintf(xs[j * 4 + 3] / s));
        ((ushort4*)qr)[g] = o;
    }
}

// ---------------- kernel 2: C[m,n] = s[m] * sum_k qi[m,k]*Wb[n,k] + bias[n] ----------------
// m97-style: 128x128 tile, BK=32, 4 waves each computing 64x64 via 4x4 MFMA 16x16x32.
__global__ __launch_bounds__(256) void gemm_kernel(
        const unsigned short* __restrict__ A,     // [M,K] bf16 (qi)
        const unsigned short* __restrict__ B,     // [N,K] bf16 (Wb)
        const float* __restrict__ scales,         // [M]
        const float* __restrict__ bias,           // [N]
        float* __restrict__ C) {                  // [M,N] f32
    const int K = K_DIM, N = N_DIM;
    __shared__ __align__(16) unsigned short As[128 * 32];
    __shared__ __align__(16) unsigned short Bs[128 * 32];

    const int tid  = threadIdx.x;
    const int tn   = blockIdx.x;          // N tile (0..31)
    const int tm   = blockIdx.y;          // M tile (0..63)
    const int lane = tid & 63, wave = tid >> 6;
    const int wr = wave >> 1, wc = wave & 1;      // 2x2 waves of 64x64
    const int quad = lane >> 4, lrow = lane & 15;

    // staging: thread t loads 16B at linear LDS offset t*16 (rows 0..63), and +4KB (rows 64..127)
    const int sr = tid >> 2;              // tile row 0..63
    const int sc = (tid & 3) * 8;         // elem col within BK
    const unsigned short* ga = A + ((size_t)(tm * 128 + sr)) * K + sc;
    const unsigned short* gb = B + ((size_t)(tn * 128 + sr)) * K + sc;
    unsigned short* la = As + tid * 8;
    unsigned short* lb = Bs + tid * 8;

    f32x4 acc[4][4];
    const f32x4 z = { 0.f, 0.f, 0.f, 0.f };
#pragma unroll
    for (int i = 0; i < 4; ++i)
#pragma unroll
        for (int j = 0; j < 4; ++j) acc[i][j] = z;

    for (int kt = 0; kt < K / 32; ++kt) {
        const int k0 = kt * 32;
        gload_lds16(ga + k0, la);
        gload_lds16(ga + k0 + (size_t)64 * K, la + 256 * 8);
        gload_lds16(gb + k0, lb);
        gload_lds16(gb + k0 + (size_t)64 * K, lb + 256 * 8);
        __syncthreads();   // compiler drains vmcnt before s_barrier

        bf16x8 af[4], bfr[4];
#pragma unroll
        for (int i = 0; i < 4; ++i)
            af[i] = *(const bf16x8*)(As + (wr * 64 + i * 16 + lrow) * 32 + quad * 8);
#pragma unroll
        for (int j = 0; j < 4; ++j)
            bfr[j] = *(const bf16x8*)(Bs + (wc * 64 + j * 16 + lrow) * 32 + quad * 8);
#pragma unroll
        for (int i = 0; i < 4; ++i)
#pragma unroll
            for (int j = 0; j < 4; ++j)
                acc[i][j] = __builtin_amdgcn_mfma_f32_16x16x32_bf16(af[i], bfr[j], acc[i][j], 0, 0, 0);
        __syncthreads();   // all reads done before next stage overwrites
    }

    // epilogue: D row = quad*4+reg, col = lane&15 (m89-verified layout)
#pragma unroll
    for (int i = 0; i < 4; ++i) {
        const int rbase = tm * 128 + wr * 64 + i * 16 + quad * 4;
#pragma unroll
        for (int j = 0; j < 4; ++j) {
            const int col = tn * 128 + wc * 64 + j * 16 + lrow;
            const float bb = bias[col];
#pragma unroll
            for (int r = 0; r < 4; ++r) {
                const int grow = rbase + r;
                C[(size_t)grow * N + col] = scales[grow] * acc[i][j][r] + bb;
            }
        }
    }
}

extern "C" void kernel_launch(void* const* d_in, const int* in_sizes, int n_in,
                              void* d_out, int out_size, void* d_ws, size_t ws_size,
                              hipStream_t stream) {
    const float* x    = (const float*)d_in[0];   // (4,2048,4096)
    const float* w    = (const float*)d_in[1];   // (4096,4096)
    const float* bias = (const float*)d_in[2];   // (1,4096)
    const float* ss   = (const float*)d_in[3];   // (1,4096)
    float* out = (float*)d_out;

    // workspace layout: qi bf16 [8192*4096] | scales f32 [8192] | Wb bf16 [4096*4096]
    unsigned short* qi = (unsigned short*)d_ws;
    float* scales = (float*)((char*)d_ws + (size_t)T_TOK * K_DIM * 2);
    unsigned short* wb = (unsigned short*)((char*)d_ws + (size_t)T_TOK * K_DIM * 2 + T_TOK * 4);

    wconv_kernel<<<(N_DIM * K_DIM) / (256 * 4), 256, 0, stream>>>(w, wb);
    sparsequant_kernel<<<T_TOK, 256, 0, stream>>>(x, ss, qi, scales);
    dim3 grid(N_DIM / 128, T_TOK / 128);
    gemm_kernel<<<grid, 256, 0, stream>>>(qi, wb, scales, bias, out);
}